// Round 7
// baseline (289.877 us; speedup 1.0000x reference)
//
#include <hip/hip_runtime.h>
#include <hip/hip_bf16.h>

#define B_SZ 16
#define C_IN 256
#define N_SP 2304
#define K_INT 128
#define NTILE 36   // q-tiles of 64
#define MT 64      // key/value m-tile per epoch (2x32 subtiles)
#define EITER 36   // N_SP / MT epochs

typedef __attribute__((ext_vector_type(8))) short short8;
typedef __attribute__((ext_vector_type(4))) float f32x4;

// bf16 weights, converted once by wcvt_kernel: [p][k][c], p=0 theta, p=1 phi
__device__ __align__(16) short g_Wbf[2 * K_INT * C_IN];

// packed fp32x2 -> bf16x2 (v_cvt_pk_bf16_f32, RNE)
__device__ inline unsigned pk_bf16(float a, float b) {
  float2 f; f.x = a; f.y = b;
  __hip_bfloat162 h = __float22bfloat162_rn(f);
  unsigned u;
  __builtin_memcpy(&u, &h, sizeof(u));
  return u;
}

// ---------------------------------------------------------------------------
// One-time weight convert: f32 -> bf16 into g_Wbf (128 KiB, L2-resident).
// ---------------------------------------------------------------------------
__global__ __launch_bounds__(256) void wcvt_kernel(
    const float* __restrict__ tw, const float* __restrict__ pw)
{
  const int i = (blockIdx.x * 256 + threadIdx.x) * 4;  // grid 32 covers 32768
  float4 a = *(const float4*)(tw + i);
  float4 p = *(const float4*)(pw + i);
  uint2 ua; ua.x = pk_bf16(a.x, a.y); ua.y = pk_bf16(a.z, a.w);
  uint2 up; up.x = pk_bf16(p.x, p.y); up.y = pk_bf16(p.z, p.w);
  *(uint2*)(g_Wbf + i) = ua;
  *(uint2*)(g_Wbf + 32768 + i) = up;
}

// ---------------------------------------------------------------------------
// Projection (byte-identical to R6): coalesced stage, swizzled LDS transpose.
// ---------------------------------------------------------------------------
__global__ __launch_bounds__(256) void proj_kernel(
    const float* __restrict__ x,
    const float* __restrict__ theta_b, const float* __restrict__ phi_b,
    short* __restrict__ Qt, short* __restrict__ Kt, short* __restrict__ Gbf)
{
  __shared__ short Xl[64][264];  // [n][c'], +8 pad

  const int b  = blockIdx.x / NTILE;
  const int n0 = (blockIdx.x % NTILE) * 64;
  const int t  = threadIdx.x;

  // ---- stage: coalesced x read / Gbf write, swizzled LDS transpose ----
  {
    const int cr = t >> 4;     // c row base, +16 per step
    const int a  = t & 15;     // n-segment (4 floats)
    const int n  = a * 4;
    const int g8 = (a & 3) << 3;  // (n>>2)&3 == a&3
    const float* xs = x + ((size_t)b * C_IN + cr) * N_SP + n0 + n;
    short* gs = Gbf + ((size_t)b * C_IN + cr) * N_SP + n0 + n;
#pragma unroll
    for (int i = 0; i < 16; ++i) {
      float4 v = *(const float4*)(xs + (size_t)i * 16 * N_SP);
      unsigned p0 = pk_bf16(v.x, v.y), p1 = pk_bf16(v.z, v.w);
      uint2 u; u.x = p0; u.y = p1;
      *(uint2*)(gs + (size_t)i * 16 * N_SP) = u;
      const int cs0 = (cr + 16 * i) ^ g8;
      Xl[n + 0][cs0] = (short)p0;
      Xl[n + 1][cs0] = (short)(p0 >> 16);
      Xl[n + 2][cs0] = (short)p1;
      Xl[n + 3][cs0] = (short)(p1 >> 16);
    }
  }
  __syncthreads();

  const int wave = t >> 6, lane = t & 63;
  const int col = lane & 15, quad = lane >> 4;
  const int rg8 = ((col >> 2) & 3) << 3;  // read-side granule XOR

  f32x4 acc[2][2][4];
#pragma unroll
  for (int p = 0; p < 2; ++p)
#pragma unroll
    for (int kr = 0; kr < 2; ++kr)
#pragma unroll
      for (int j = 0; j < 4; ++j) {
        acc[p][kr][j][0] = 0.f; acc[p][kr][j][1] = 0.f;
        acc[p][kr][j][2] = 0.f; acc[p][kr][j][3] = 0.f;
      }

#pragma unroll
  for (int cs = 0; cs < 8; ++cs) {
    const int c0 = cs * 32;
    short8 afr[2][2];
#pragma unroll
    for (int p = 0; p < 2; ++p)
#pragma unroll
      for (int kr = 0; kr < 2; ++kr) {
        const int k = wave * 32 + kr * 16 + col;
        afr[p][kr] = *(const short8*)(g_Wbf + p * 32768 + k * C_IN + c0 + quad * 8);
      }
#pragma unroll
    for (int j = 0; j < 4; ++j) {
      short8 bfr = *(const short8*)&Xl[j * 16 + col][(c0 + quad * 8) ^ rg8];
#pragma unroll
      for (int p = 0; p < 2; ++p)
#pragma unroll
        for (int kr = 0; kr < 2; ++kr)
          acc[p][kr][j] = __builtin_amdgcn_mfma_f32_16x16x32_bf16(
              afr[p][kr], bfr, acc[p][kr][j], 0, 0, 0);
    }
  }

  // ---- epilogue: bias + transpose-store to [b][n][k] bf16 ----
#pragma unroll
  for (int p = 0; p < 2; ++p) {
    const float* bias = p ? phi_b : theta_b;
    short* dst = p ? Kt : Qt;
#pragma unroll
    for (int kr = 0; kr < 2; ++kr) {
      const int k0 = wave * 32 + kr * 16 + quad * 4;
      float4 bv = *(const float4*)(bias + k0);
#pragma unroll
      for (int j = 0; j < 4; ++j) {
        const int n = n0 + j * 16 + col;
        f32x4 v = acc[p][kr][j];
        uint2 sv;
        sv.x = pk_bf16(v[0] + bv.x, v[1] + bv.y);
        sv.y = pk_bf16(v[2] + bv.z, v[3] + bv.w);
        *(uint2*)(dst + ((size_t)b * N_SP + n) * K_INT + k0) = sv;
      }
    }
  }
}

// ---------------------------------------------------------------------------
// Flash attention v7 = R4's exact schedule (measured 147us) with MT=64:
// two 32-m subtiles per epoch, ONE barrier per epoch (72 -> 36 barriers).
// Per-m-row MFMA/DS/VMEM counts identical to R4; only the per-epoch fixed
// cost (barrier + vmcnt drain + skew, modeled ~1700cy) is amortized 2x.
// Ordering preserved: [QK, softmax, Pwrite, Kstage, Kpref, Gpref, BAR, PV]
// (R6 proved moving prefetches after the barrier costs +28us: collective
// drain at the barrier beats per-wave mid-epoch waits).
// No XCD swizzle (R6: -100MB FETCH, 0 time gain -> fetch not binding).
// ---------------------------------------------------------------------------
__global__ __launch_bounds__(256) void attn_kernel(
    const short* __restrict__ Qt, const short* __restrict__ Kt,
    const short* __restrict__ Gbf, float* __restrict__ out)
{
  __shared__ __align__(16) char Kl[2][16384];            // [buf][64 m][128 k] swz
  __shared__ __align__(16) short Pblob[2][4][2][64][8];  // [buf][wave][half][lane][8]
  __shared__ float l_lds[64];

  const int b   = blockIdx.x / NTILE;
  const int qn0 = (blockIdx.x % NTILE) * 64;
  const int t = threadIdx.x;
  const int wave = t >> 6, lane = t & 63;
  const int col = lane & 15, quad = lane >> 4;

  const short* Ktb = Kt  + (size_t)b * N_SP * K_INT;
  const short* Gb  = Gbf + (size_t)b * C_IN * N_SP;

  // Q fragments in registers for the whole loop (B-operand layout: col=q)
  short8 qf[4];
  {
    const short* qb = Qt + ((size_t)b * N_SP + qn0 + wave * 16 + col) * K_INT + quad * 8;
#pragma unroll
    for (int kk = 0; kk < 4; ++kk) qf[kk] = *(const short8*)(qb + kk * 32);
  }

  f32x4 yacc[4][4];  // [q-tile][c-tile]
#pragma unroll
  for (int i = 0; i < 4; ++i)
#pragma unroll
    for (int j = 0; j < 4; ++j) {
      yacc[i][j][0] = 0.f; yacc[i][j][1] = 0.f;
      yacc[i][j][2] = 0.f; yacc[i][j][3] = 0.f;
    }
  f32x4 lacc;
  lacc[0] = 0.f; lacc[1] = 0.f; lacc[2] = 0.f; lacc[3] = 0.f;

  short8 ones;
#pragma unroll
  for (int j = 0; j < 8; ++j) ones[j] = (short)0x3F80;  // bf16 1.0

  const float SC2 = 0.12754859f;  // (1/sqrt(128)) * log2(e)

  // ---- K LDS offsets: phys(r,chunk) = r*256 + ((chunk ^ (r&7))<<4) ----
  // stage rows t>>4 + 16i: (row&7) invariant -> +i*4096 immediates
  const int KW = (t >> 4) * 256 + ((((t & 15) ^ ((t >> 4) & 7))) << 4);
  // QK read rows col + 16h: (row&7) invariant -> +h*4096 immediates
  int KR0[4];
#pragma unroll
  for (int kk = 0; kk < 4; ++kk)
    KR0[kk] = col * 256 + ((((kk << 2) + quad) ^ (col & 7)) << 4);

  // ---- global offsets ----
  const int KG = (t >> 4) * K_INT + (t & 15) * 8;  // K stage rows t>>4 (+16i)
  const short* gbase = Gb + ((size_t)(wave * 64 + col)) * N_SP + quad * 8;

  // ---- prologue: epoch0 -> Kl[0]; kr <- epoch1; gA <- G epoch0 ----
  short8 kr[4];
#pragma unroll
  for (int i = 0; i < 4; ++i) kr[i] = *(const short8*)(Ktb + KG + i * 2048);
#pragma unroll
  for (int i = 0; i < 4; ++i) *(short8*)(Kl[0] + KW + i * 4096) = kr[i];
#pragma unroll
  for (int i = 0; i < 4; ++i) kr[i] = *(const short8*)(Ktb + 8192 + KG + i * 2048);
  short8 gA[8], gB[8];
#pragma unroll
  for (int i = 0; i < 8; ++i)  // i = h*4+ct: m-half h, c-tile ct
    gA[i] = *(const short8*)(gbase + (size_t)(i & 3) * 16 * N_SP + (i >> 2) * 32);
  __syncthreads();

#define EPOCH(EV, CUR, GC, GN)                                                 \
  {                                                                            \
    /* 1. QK: S[h] = K(rows 64*EV+16h..+16) x Q, h=0..3 */                     \
    f32x4 s[4];                                                                \
    _Pragma("unroll")                                                          \
    for (int h = 0; h < 4; ++h) {                                              \
      s[h][0] = 0.f; s[h][1] = 0.f; s[h][2] = 0.f; s[h][3] = 0.f;              \
    }                                                                          \
    _Pragma("unroll")                                                          \
    for (int kk = 0; kk < 4; ++kk) {                                           \
      _Pragma("unroll")                                                        \
      for (int h = 0; h < 4; ++h) {                                            \
        short8 a0 = *(const short8*)(Kl[CUR] + KR0[kk] + h * 4096);            \
        s[h] = __builtin_amdgcn_mfma_f32_16x16x32_bf16(a0, qf[kk], s[h],       \
                                                       0, 0, 0);               \
      }                                                                        \
    }                                                                          \
    /* 2. softmax-lite + in-register transpose, two 32-m halves */             \
    short8 pa0, pa1;                                                           \
    {                                                                          \
      unsigned u0 = pk_bf16(exp2f(s[0][0] * SC2), exp2f(s[0][1] * SC2));       \
      unsigned u1 = pk_bf16(exp2f(s[0][2] * SC2), exp2f(s[0][3] * SC2));       \
      unsigned u2 = pk_bf16(exp2f(s[1][0] * SC2), exp2f(s[1][1] * SC2));       \
      unsigned u3 = pk_bf16(exp2f(s[1][2] * SC2), exp2f(s[1][3] * SC2));       \
      asm("v_permlane32_swap_b32 %0, %1" : "+v"(u0), "+v"(u2));                \
      asm("v_permlane32_swap_b32 %0, %1" : "+v"(u1), "+v"(u3));                \
      asm("v_permlane16_swap_b32 %0, %1" : "+v"(u0), "+v"(u2));                \
      asm("v_permlane16_swap_b32 %0, %1" : "+v"(u1), "+v"(u3));                \
      unsigned uu[4] = {u0, u1, u2, u3};                                       \
      __builtin_memcpy(&pa0, uu, 16);                                          \
      unsigned v0 = pk_bf16(exp2f(s[2][0] * SC2), exp2f(s[2][1] * SC2));       \
      unsigned v1 = pk_bf16(exp2f(s[2][2] * SC2), exp2f(s[2][3] * SC2));       \
      unsigned v2 = pk_bf16(exp2f(s[3][0] * SC2), exp2f(s[3][1] * SC2));       \
      unsigned v3 = pk_bf16(exp2f(s[3][2] * SC2), exp2f(s[3][3] * SC2));       \
      asm("v_permlane32_swap_b32 %0, %1" : "+v"(v0), "+v"(v2));                \
      asm("v_permlane32_swap_b32 %0, %1" : "+v"(v1), "+v"(v3));                \
      asm("v_permlane16_swap_b32 %0, %1" : "+v"(v0), "+v"(v2));                \
      asm("v_permlane16_swap_b32 %0, %1" : "+v"(v1), "+v"(v3));                \
      unsigned vv[4] = {v0, v1, v2, v3};                                       \
      __builtin_memcpy(&pa1, vv, 16);                                          \
    }                                                                          \
    lacc = __builtin_amdgcn_mfma_f32_16x16x32_bf16(pa0, ones, lacc, 0, 0, 0);  \
    lacc = __builtin_amdgcn_mfma_f32_16x16x32_bf16(pa1, ones, lacc, 0, 0, 0);  \
    /* 3. P exchange writes (lane-linear, conflict-free) */                    \
    *(short8*)&Pblob[CUR][wave][0][lane][0] = pa0;                             \
    *(short8*)&Pblob[CUR][wave][1][lane][0] = pa1;                             \
    /* 4. K stage: epoch EV+1 -> Kl[CUR^1] (kr loaded last epoch: landed) */   \
    if ((EV) + 1 < EITER) {                                                    \
      _Pragma("unroll")                                                        \
      for (int i = 0; i < 4; ++i)                                              \
        *(short8*)(Kl[(CUR) ^ 1] + KW + i * 4096) = kr[i];                     \
    }                                                                          \
    /* 5. K global prefetch: epoch EV+2 (staged next epoch) */                 \
    if ((EV) + 2 < EITER) {                                                    \
      const short* kp = Ktb + (size_t)((EV) + 2) * 8192 + KG;                  \
      _Pragma("unroll")                                                        \
      for (int i = 0; i < 4; ++i) kr[i] = *(const short8*)(kp + i * 2048);     \
    }                                                                          \
    /* 6. G global prefetch: epoch EV+1 (consumed next epoch's PV) */          \
    if ((EV) + 1 < EITER) {                                                    \
      _Pragma("unroll")                                                        \
      for (int i = 0; i < 8; ++i)                                              \
        GN[i] = *(const short8*)(gbase + (size_t)(i & 3) * 16 * N_SP +         \
                                 ((EV) + 1) * 64 + (i >> 2) * 32);             \
    }                                                                          \
    __syncthreads();                                                           \
    /* 7. PV: Y[q][c] += P[q][m] G^T[m][c], both m-halves (G regs) */          \
    _Pragma("unroll")                                                          \
    for (int qt = 0; qt < 4; ++qt) {                                           \
      short8 paq0 = *(const short8*)&Pblob[CUR][qt][0][lane][0];               \
      short8 paq1 = *(const short8*)&Pblob[CUR][qt][1][lane][0];               \
      _Pragma("unroll")                                                        \
      for (int ct = 0; ct < 4; ++ct) {                                         \
        yacc[qt][ct] = __builtin_amdgcn_mfma_f32_16x16x32_bf16(                \
            paq0, GC[ct], yacc[qt][ct], 0, 0, 0);                              \
        yacc[qt][ct] = __builtin_amdgcn_mfma_f32_16x16x32_bf16(                \
            paq1, GC[4 + ct], yacc[qt][ct], 0, 0, 0);                          \
      }                                                                        \
    }                                                                          \
  }

  for (int e2 = 0; e2 < EITER / 2; ++e2) {
    EPOCH(2 * e2,     0, gA, gB)
    EPOCH(2 * e2 + 1, 1, gB, gA)
  }
#undef EPOCH

  // ---- l exchange: wave w holds l[16w + quad*4 + r] in lacc[r] ----
  if (col == 0) {
#pragma unroll
    for (int r = 0; r < 4; ++r) l_lds[wave * 16 + quad * 4 + r] = lacc[r];
  }
  __syncthreads();

  // ---- epilogue: normalize and store out[b][c][n]; c = wave*64+ct*16+col ----
#pragma unroll
  for (int qt = 0; qt < 4; ++qt) {
    float4 lq = *(const float4*)&l_lds[qt * 16 + quad * 4];
    float4 iv;
    iv.x = 1.0f / lq.x; iv.y = 1.0f / lq.y; iv.z = 1.0f / lq.z; iv.w = 1.0f / lq.w;
    const int nb = qn0 + qt * 16 + quad * 4;
#pragma unroll
    for (int ct = 0; ct < 4; ++ct) {
      const int c = wave * 64 + ct * 16 + col;
      f32x4 v = yacc[qt][ct];
      float4 o;
      o.x = v[0] * iv.x; o.y = v[1] * iv.y; o.z = v[2] * iv.z; o.w = v[3] * iv.w;
      *(float4*)(out + ((size_t)b * C_IN + c) * N_SP + nb) = o;
    }
  }
}

extern "C" void kernel_launch(void* const* d_in, const int* in_sizes, int n_in,
                              void* d_out, int out_size, void* d_ws, size_t ws_size,
                              hipStream_t stream) {
  const float* x  = (const float*)d_in[0];
  const float* tw = (const float*)d_in[1];
  const float* tb = (const float*)d_in[2];
  const float* pw = (const float*)d_in[3];
  const float* pb = (const float*)d_in[4];
  float* out = (float*)d_out;

  // workspace: Qt (9.4MB) | Kt (9.4MB) | Gbf (18.9MB) = 37.75 MB total
  short* Qt  = (short*)d_ws;
  short* Kt  = Qt + (size_t)B_SZ * N_SP * K_INT;
  short* Gbf = Kt + (size_t)B_SZ * N_SP * K_INT;

  wcvt_kernel<<<32, 256, 0, stream>>>(tw, pw);
  proj_kernel<<<B_SZ * NTILE, 256, 0, stream>>>(x, tb, pb, Qt, Kt, Gbf);
  attn_kernel<<<B_SZ * NTILE, 256, 0, stream>>>(Qt, Kt, Gbf, out);
}

// Round 8
// 241.216 us; speedup vs baseline: 1.2017x; 1.2017x over previous
//
#include <hip/hip_runtime.h>
#include <hip/hip_bf16.h>

#define B_SZ 16
#define C_IN 256
#define N_SP 2304
#define K_INT 128
#define NTILE 36  // q-tiles of 64
#define MT 32     // key/value m-tile
#define MITER 72  // N_SP / MT

typedef __attribute__((ext_vector_type(8))) short short8;
typedef __attribute__((ext_vector_type(4))) float f32x4;

// bf16 weights, converted once by wcvt_kernel: [p][k][c], p=0 theta, p=1 phi
__device__ __align__(16) short g_Wbf[2 * K_INT * C_IN];

// packed fp32x2 -> bf16x2 (v_cvt_pk_bf16_f32, RNE)
__device__ inline unsigned pk_bf16(float a, float b) {
  float2 f; f.x = a; f.y = b;
  __hip_bfloat162 h = __float22bfloat162_rn(f);
  unsigned u;
  __builtin_memcpy(&u, &h, sizeof(u));
  return u;
}

// barrier that drains LDS ops only -- NO vmcnt(0): register-destined global
// prefetches survive across it (compiler inserts counted vmcnt at use).
__device__ inline void barrier_lgkm() {
  asm volatile("s_waitcnt lgkmcnt(0)" ::: "memory");
  __builtin_amdgcn_s_barrier();
  asm volatile("" ::: "memory");  // pin post-barrier LDS reads below barrier
}

// ---------------------------------------------------------------------------
// One-time weight convert: f32 -> bf16 into g_Wbf (128 KiB, L2-resident).
// ---------------------------------------------------------------------------
__global__ __launch_bounds__(256) void wcvt_kernel(
    const float* __restrict__ tw, const float* __restrict__ pw)
{
  const int i = (blockIdx.x * 256 + threadIdx.x) * 4;  // grid 32 covers 32768
  float4 a = *(const float4*)(tw + i);
  float4 p = *(const float4*)(pw + i);
  uint2 ua; ua.x = pk_bf16(a.x, a.y); ua.y = pk_bf16(a.z, a.w);
  uint2 up; up.x = pk_bf16(p.x, p.y); up.y = pk_bf16(p.z, p.w);
  *(uint2*)(g_Wbf + i) = ua;
  *(uint2*)(g_Wbf + 32768 + i) = up;
}

// ---------------------------------------------------------------------------
// Projection (byte-identical to R6): coalesced stage, swizzled LDS transpose.
// ---------------------------------------------------------------------------
__global__ __launch_bounds__(256) void proj_kernel(
    const float* __restrict__ x,
    const float* __restrict__ theta_b, const float* __restrict__ phi_b,
    short* __restrict__ Qt, short* __restrict__ Kt, short* __restrict__ Gbf)
{
  __shared__ short Xl[64][264];  // [n][c'], +8 pad

  const int b  = blockIdx.x / NTILE;
  const int n0 = (blockIdx.x % NTILE) * 64;
  const int t  = threadIdx.x;

  // ---- stage: coalesced x read / Gbf write, swizzled LDS transpose ----
  {
    const int cr = t >> 4;     // c row base, +16 per step
    const int a  = t & 15;     // n-segment (4 floats)
    const int n  = a * 4;
    const int g8 = (a & 3) << 3;  // (n>>2)&3 == a&3
    const float* xs = x + ((size_t)b * C_IN + cr) * N_SP + n0 + n;
    short* gs = Gbf + ((size_t)b * C_IN + cr) * N_SP + n0 + n;
#pragma unroll
    for (int i = 0; i < 16; ++i) {
      float4 v = *(const float4*)(xs + (size_t)i * 16 * N_SP);
      unsigned p0 = pk_bf16(v.x, v.y), p1 = pk_bf16(v.z, v.w);
      uint2 u; u.x = p0; u.y = p1;
      *(uint2*)(gs + (size_t)i * 16 * N_SP) = u;
      const int cs0 = (cr + 16 * i) ^ g8;
      Xl[n + 0][cs0] = (short)p0;
      Xl[n + 1][cs0] = (short)(p0 >> 16);
      Xl[n + 2][cs0] = (short)p1;
      Xl[n + 3][cs0] = (short)(p1 >> 16);
    }
  }
  __syncthreads();

  const int wave = t >> 6, lane = t & 63;
  const int col = lane & 15, quad = lane >> 4;
  const int rg8 = ((col >> 2) & 3) << 3;  // read-side granule XOR

  f32x4 acc[2][2][4];
#pragma unroll
  for (int p = 0; p < 2; ++p)
#pragma unroll
    for (int kr = 0; kr < 2; ++kr)
#pragma unroll
      for (int j = 0; j < 4; ++j) {
        acc[p][kr][j][0] = 0.f; acc[p][kr][j][1] = 0.f;
        acc[p][kr][j][2] = 0.f; acc[p][kr][j][3] = 0.f;
      }

#pragma unroll
  for (int cs = 0; cs < 8; ++cs) {
    const int c0 = cs * 32;
    short8 afr[2][2];
#pragma unroll
    for (int p = 0; p < 2; ++p)
#pragma unroll
      for (int kr = 0; kr < 2; ++kr) {
        const int k = wave * 32 + kr * 16 + col;
        afr[p][kr] = *(const short8*)(g_Wbf + p * 32768 + k * C_IN + c0 + quad * 8);
      }
#pragma unroll
    for (int j = 0; j < 4; ++j) {
      short8 bfr = *(const short8*)&Xl[j * 16 + col][(c0 + quad * 8) ^ rg8];
#pragma unroll
      for (int p = 0; p < 2; ++p)
#pragma unroll
        for (int kr = 0; kr < 2; ++kr)
          acc[p][kr][j] = __builtin_amdgcn_mfma_f32_16x16x32_bf16(
              afr[p][kr], bfr, acc[p][kr][j], 0, 0, 0);
    }
  }

  // ---- epilogue: bias + transpose-store to [b][n][k] bf16 ----
#pragma unroll
  for (int p = 0; p < 2; ++p) {
    const float* bias = p ? phi_b : theta_b;
    short* dst = p ? Kt : Qt;
#pragma unroll
    for (int kr = 0; kr < 2; ++kr) {
      const int k0 = wave * 32 + kr * 16 + quad * 4;
      float4 bv = *(const float4*)(bias + k0);
#pragma unroll
      for (int j = 0; j < 4; ++j) {
        const int n = n0 + j * 16 + col;
        f32x4 v = acc[p][kr][j];
        uint2 sv;
        sv.x = pk_bf16(v[0] + bv.x, v[1] + bv.y);
        sv.y = pk_bf16(v[2] + bv.z, v[3] + bv.w);
        *(uint2*)(dst + ((size_t)b * N_SP + n) * K_INT + k0) = sv;
      }
    }
  }
}

// ---------------------------------------------------------------------------
// Flash attention v8 = R4-EXACT structure (measured 147us) with ONE change:
// the loop barrier drains lgkmcnt only (no vmcnt). R4's K/G register
// prefetches, issued just before the barrier, were drained to zero lead by
// __syncthreads' vmcnt(0) -- all 12 waves/CU collectively ate L2 latency
// every iteration (this also explains R3's and R6's regressions). With the
// lgkm-only barrier the prefetches keep a full-iteration lead; the compiler
// inserts counted vmcnt waits at the consumption points automatically.
// Race audit: P-write->P-read and Kstage->QK-read ordered by lgkm drain +
// barrier; LDS buffer reuse is 2 epochs away across a drained barrier;
// kr/G registers are same-wave vmcnt-tracked. No cross-wave global data.
// ---------------------------------------------------------------------------
__global__ __launch_bounds__(256) void attn_kernel(
    const short* __restrict__ Qt, const short* __restrict__ Kt,
    const short* __restrict__ Gbf, float* __restrict__ out)
{
  __shared__ __align__(16) char Kl[2][8192];          // [buf][32 m][128 k] swz
  __shared__ __align__(16) short Pblob[2][4][64][8];  // [buf][wave][lane][8]
  __shared__ float l_lds[64];

  const int b   = blockIdx.x / NTILE;
  const int qn0 = (blockIdx.x % NTILE) * 64;
  const int t = threadIdx.x;
  const int wave = t >> 6, lane = t & 63;
  const int col = lane & 15, quad = lane >> 4;

  const short* Ktb = Kt  + (size_t)b * N_SP * K_INT;
  const short* Gb  = Gbf + (size_t)b * C_IN * N_SP;

  // Q fragments in registers for the whole loop (B-operand layout: col=q)
  short8 qf[4];
  {
    const short* qb = Qt + ((size_t)b * N_SP + qn0 + wave * 16 + col) * K_INT + quad * 8;
#pragma unroll
    for (int kk = 0; kk < 4; ++kk) qf[kk] = *(const short8*)(qb + kk * 32);
  }

  f32x4 yacc[4][4];  // [q-tile][c-tile]
#pragma unroll
  for (int i = 0; i < 4; ++i)
#pragma unroll
    for (int j = 0; j < 4; ++j) {
      yacc[i][j][0] = 0.f; yacc[i][j][1] = 0.f;
      yacc[i][j][2] = 0.f; yacc[i][j][3] = 0.f;
    }
  f32x4 lacc;
  lacc[0] = 0.f; lacc[1] = 0.f; lacc[2] = 0.f; lacc[3] = 0.f;

  short8 ones;
#pragma unroll
  for (int j = 0; j < 8; ++j) ones[j] = (short)0x3F80;  // bf16 1.0

  const float SC2 = 0.12754859f;  // (1/sqrt(128)) * log2(e)

  // ---- K LDS offsets: phys(r,chunk) = r*256 + ((chunk ^ (r&7))<<4) ----
  const int KW = (t >> 4) * 256 + ((((t & 15) ^ ((t >> 4) & 7))) << 4);
  int KR0[4];
#pragma unroll
  for (int kk = 0; kk < 4; ++kk)
    KR0[kk] = col * 256 + ((((kk << 2) + quad) ^ (col & 7)) << 4);

  // ---- global offsets ----
  const int koff = (t >> 4) * K_INT + (t & 15) * 8;  // K stage rows t>>4 / +16
  const short* gbase = Gb + ((size_t)(wave * 64 + col)) * N_SP + quad * 8;

  // ---- prologue: tile0 -> Kl[0]; kr <- tile1; gA <- G tile0 ----
  short8 krA, krB;
  krA = *(const short8*)(Ktb + koff);
  krB = *(const short8*)(Ktb + 2048 + koff);
  *(short8*)(Kl[0] + KW) = krA;
  *(short8*)(Kl[0] + KW + 4096) = krB;
  krA = *(const short8*)(Ktb + 4096 + koff);
  krB = *(const short8*)(Ktb + 6144 + koff);
  short8 gA[4], gB[4];
#pragma unroll
  for (int ct = 0; ct < 4; ++ct)
    gA[ct] = *(const short8*)(gbase + (size_t)ct * 16 * N_SP);
  barrier_lgkm();

#define SUBITER(MTV, CUR, GC, GN)                                              \
  {                                                                            \
    /* 1. QK: S = K(tile MTV) x Q  (A-frags from LDS) */                       \
    f32x4 s0, s1;                                                              \
    s0[0] = 0.f; s0[1] = 0.f; s0[2] = 0.f; s0[3] = 0.f;                        \
    s1[0] = 0.f; s1[1] = 0.f; s1[2] = 0.f; s1[3] = 0.f;                        \
    _Pragma("unroll")                                                          \
    for (int kk = 0; kk < 4; ++kk) {                                           \
      short8 a0 = *(const short8*)(Kl[CUR] + KR0[kk]);                         \
      s0 = __builtin_amdgcn_mfma_f32_16x16x32_bf16(a0, qf[kk], s0, 0, 0, 0);   \
      short8 a1 = *(const short8*)(Kl[CUR] + KR0[kk] + 4096);                  \
      s1 = __builtin_amdgcn_mfma_f32_16x16x32_bf16(a1, qf[kk], s1, 0, 0, 0);   \
    }                                                                          \
    /* 2. softmax-lite + in-register transpose to A-fragment */                \
    unsigned u0 = pk_bf16(exp2f(s0[0] * SC2), exp2f(s0[1] * SC2));             \
    unsigned u1 = pk_bf16(exp2f(s0[2] * SC2), exp2f(s0[3] * SC2));             \
    unsigned u2 = pk_bf16(exp2f(s1[0] * SC2), exp2f(s1[1] * SC2));             \
    unsigned u3 = pk_bf16(exp2f(s1[2] * SC2), exp2f(s1[3] * SC2));             \
    asm("v_permlane32_swap_b32 %0, %1" : "+v"(u0), "+v"(u2));                  \
    asm("v_permlane32_swap_b32 %0, %1" : "+v"(u1), "+v"(u3));                  \
    asm("v_permlane16_swap_b32 %0, %1" : "+v"(u0), "+v"(u2));                  \
    asm("v_permlane16_swap_b32 %0, %1" : "+v"(u1), "+v"(u3));                  \
    unsigned uu[4] = {u0, u1, u2, u3};                                         \
    short8 pa; __builtin_memcpy(&pa, uu, 16);                                  \
    lacc = __builtin_amdgcn_mfma_f32_16x16x32_bf16(pa, ones, lacc, 0, 0, 0);   \
    /* 3. P exchange write (lane-linear, conflict-free) */                     \
    *(short8*)&Pblob[CUR][wave][lane][0] = pa;                                 \
    /* 4. K stage: tile MTV+1 -> Kl[CUR^1] (kr loaded LAST iter: landed) */    \
    if ((MTV) + 1 < MITER) {                                                   \
      *(short8*)(Kl[(CUR) ^ 1] + KW) = krA;                                    \
      *(short8*)(Kl[(CUR) ^ 1] + KW + 4096) = krB;                             \
    }                                                                          \
    /* 5. K global prefetch: tile MTV+2 (staged next iter) */                  \
    if ((MTV) + 2 < MITER) {                                                   \
      const short* kp = Ktb + (size_t)((MTV) + 2) * 4096 + koff;               \
      krA = *(const short8*)(kp);                                              \
      krB = *(const short8*)(kp + 2048);                                       \
    }                                                                          \
    /* 6. G global prefetch: tile MTV+1 (consumed next iter's PV) */           \
    if ((MTV) + 1 < MITER) {                                                   \
      _Pragma("unroll")                                                        \
      for (int ct = 0; ct < 4; ++ct)                                           \
        GN[ct] = *(const short8*)(gbase + (size_t)ct * 16 * N_SP +             \
                                  ((MTV) + 1) * 32);                           \
    }                                                                          \
    /* 7. barrier: LDS visibility only; vmcnt floats across (the fix) */       \
    barrier_lgkm();                                                            \
    /* 8. PV: Y[q][c] += P[q][m] G^T[m][c]  (G regs, P lane-linear) */         \
    _Pragma("unroll")                                                          \
    for (int qt = 0; qt < 4; ++qt) {                                           \
      short8 paq = *(const short8*)&Pblob[CUR][qt][lane][0];                   \
      _Pragma("unroll")                                                        \
      for (int ct = 0; ct < 4; ++ct)                                           \
        yacc[qt][ct] = __builtin_amdgcn_mfma_f32_16x16x32_bf16(                \
            paq, GC[ct], yacc[qt][ct], 0, 0, 0);                               \
    }                                                                          \
  }

  for (int mt2 = 0; mt2 < MITER / 2; ++mt2) {
    SUBITER(2 * mt2,     0, gA, gB)
    SUBITER(2 * mt2 + 1, 1, gB, gA)
  }
#undef SUBITER

  // ---- l exchange: wave w holds l[16w + quad*4 + r] in lacc[r] ----
  if (col == 0) {
#pragma unroll
    for (int r = 0; r < 4; ++r) l_lds[wave * 16 + quad * 4 + r] = lacc[r];
  }
  __syncthreads();

  // ---- epilogue: normalize and store out[b][c][n]; c = wave*64+ct*16+col ----
#pragma unroll
  for (int qt = 0; qt < 4; ++qt) {
    float4 lq = *(const float4*)&l_lds[qt * 16 + quad * 4];
    float4 iv;
    iv.x = 1.0f / lq.x; iv.y = 1.0f / lq.y; iv.z = 1.0f / lq.z; iv.w = 1.0f / lq.w;
    const int nb = qn0 + qt * 16 + quad * 4;
#pragma unroll
    for (int ct = 0; ct < 4; ++ct) {
      const int c = wave * 64 + ct * 16 + col;
      f32x4 v = yacc[qt][ct];
      float4 o;
      o.x = v[0] * iv.x; o.y = v[1] * iv.y; o.z = v[2] * iv.z; o.w = v[3] * iv.w;
      *(float4*)(out + ((size_t)b * C_IN + c) * N_SP + nb) = o;
    }
  }
}

extern "C" void kernel_launch(void* const* d_in, const int* in_sizes, int n_in,
                              void* d_out, int out_size, void* d_ws, size_t ws_size,
                              hipStream_t stream) {
  const float* x  = (const float*)d_in[0];
  const float* tw = (const float*)d_in[1];
  const float* tb = (const float*)d_in[2];
  const float* pw = (const float*)d_in[3];
  const float* pb = (const float*)d_in[4];
  float* out = (float*)d_out;

  // workspace: Qt (9.4MB) | Kt (9.4MB) | Gbf (18.9MB) = 37.75 MB total
  short* Qt  = (short*)d_ws;
  short* Kt  = Qt + (size_t)B_SZ * N_SP * K_INT;
  short* Gbf = Kt + (size_t)B_SZ * N_SP * K_INT;

  wcvt_kernel<<<32, 256, 0, stream>>>(tw, pw);
  proj_kernel<<<B_SZ * NTILE, 256, 0, stream>>>(x, tb, pb, Qt, Kt, Gbf);
  attn_kernel<<<B_SZ * NTILE, 256, 0, stream>>>(Qt, Kt, Gbf, out);
}

// Round 11
// 240.074 us; speedup vs baseline: 1.2074x; 1.0048x over previous
//
#include <hip/hip_runtime.h>
#include <hip/hip_bf16.h>

#define B_SZ 16
#define C_IN 256
#define N_SP 2304
#define K_INT 128
#define NTILE 36  // q-tiles of 64
#define MT 32     // key/value m-tile
#define MITER 72  // N_SP / MT

typedef __attribute__((ext_vector_type(8))) short short8;
typedef __attribute__((ext_vector_type(4))) float f32x4;

// bf16 weights, converted once by wcvt_kernel: [p][k][c], p=0 theta, p=1 phi
__device__ __align__(16) short g_Wbf[2 * K_INT * C_IN];

// packed fp32x2 -> bf16x2 (v_cvt_pk_bf16_f32, RNE)
__device__ inline unsigned pk_bf16(float a, float b) {
  float2 f; f.x = a; f.y = b;
  __hip_bfloat162 h = __float22bfloat162_rn(f);
  unsigned u;
  __builtin_memcpy(&u, &h, sizeof(u));
  return u;
}

// ---------------------------------------------------------------------------
// One-time weight convert: f32 -> bf16 into g_Wbf (128 KiB, L2-resident).
// ---------------------------------------------------------------------------
__global__ __launch_bounds__(256) void wcvt_kernel(
    const float* __restrict__ tw, const float* __restrict__ pw)
{
  const int i = (blockIdx.x * 256 + threadIdx.x) * 4;  // grid 32 covers 32768
  float4 a = *(const float4*)(tw + i);
  float4 p = *(const float4*)(pw + i);
  uint2 ua; ua.x = pk_bf16(a.x, a.y); ua.y = pk_bf16(a.z, a.w);
  uint2 up; up.x = pk_bf16(p.x, p.y); up.y = pk_bf16(p.z, p.w);
  *(uint2*)(g_Wbf + i) = ua;
  *(uint2*)(g_Wbf + 32768 + i) = up;
}

// ---------------------------------------------------------------------------
// Projection v7 (clean trial; R9's failure is now attributed to setprio):
//  - stage: 4c x 4n micro-tile per thread -> in-register pack -> 16
//    ds_write_b64 (replaces 64 ds_write_b16 with 4 lanes/short-address =
//    serialized, present in every proj since R0)
//  - Xs: pad-free [64 n][512 B], 16B-chunk swizzle chunk ^= (n ^ (n>>2))&7.
//    Enumerated: b64 writes uniform 4 slots/bank; b128 GEMM reads uniform.
//  - weights double-buffered one cs ahead; first batch issued pre-stage
//  - epilogue: LDS bounce (reuse Xs as PB[64][256B], granule swizzle
//    g ^ (n&7) ^ ((n>>3&1)<<3), bijective both sides) -> b128 stores.
//  Values bit-identical to v6 (same cvt, same MFMA order): absmax must stay
//  4.882812e-4 exactly; any drift = layout bug.
// ---------------------------------------------------------------------------
__global__ __launch_bounds__(256) void proj_kernel(
    const float* __restrict__ x,
    const float* __restrict__ theta_b, const float* __restrict__ phi_b,
    short* __restrict__ Qt, short* __restrict__ Kt, short* __restrict__ Gbf)
{
  __shared__ __align__(16) char Xs[32768];  // [64 n][512 B] swizzled

  const int b  = blockIdx.x / NTILE;
  const int n0 = (blockIdx.x % NTILE) * 64;
  const int t  = threadIdx.x;
  const int wave = t >> 6, lane = t & 63;
  const int col = lane & 15, quad = lane >> 4;

  // ---- weight prefetch for cs=0 (lands during stage) ----
  short8 afr[2][2][2];  // [buf][p][kr]
#pragma unroll
  for (int p = 0; p < 2; ++p)
#pragma unroll
    for (int kr = 0; kr < 2; ++kr) {
      const int k = wave * 32 + kr * 16 + col;
      afr[0][p][kr] = *(const short8*)(g_Wbf + p * 32768 + k * C_IN + quad * 8);
    }

  // ---- stage: coalesced loads, in-register 4x4 pack, b64 LDS writes ----
  {
    const int tq = t >> 4;   // c-row group
    const int a  = t & 15;   // n-segment (4 floats)
    const float* xs = x + ((size_t)b * C_IN + tq * 4) * N_SP + n0 + a * 4;
    short* gs = Gbf + ((size_t)b * C_IN + tq * 4) * N_SP + n0 + a * 4;
#pragma unroll
    for (int s = 0; s < 4; ++s) {  // c-base = s*64 + tq*4
      unsigned us[4][2];
#pragma unroll
      for (int r = 0; r < 4; ++r) {
        float4 v = *(const float4*)(xs + ((size_t)s * 64 + r) * N_SP);
        us[r][0] = pk_bf16(v.x, v.y);
        us[r][1] = pk_bf16(v.z, v.w);
        uint2 u; u.x = us[r][0]; u.y = us[r][1];
        *(uint2*)(gs + ((size_t)s * 64 + r) * N_SP) = u;
      }
      const int chunk = 8 * s + (tq >> 1);
      const int half8 = (tq & 1) * 8;
#pragma unroll
      for (int j = 0; j < 4; ++j) {
        const int w = j >> 1;
        unsigned w0, w1;
        if ((j & 1) == 0) {
          w0 = (us[0][w] & 0xffffu) | (us[1][w] << 16);
          w1 = (us[2][w] & 0xffffu) | (us[3][w] << 16);
        } else {
          w0 = (us[0][w] >> 16) | (us[1][w] & 0xffff0000u);
          w1 = (us[2][w] >> 16) | (us[3][w] & 0xffff0000u);
        }
        const int n = 4 * a + j;
        const int msk = (n ^ a) & 7;  // (n ^ (n>>2)) & 7
        uint2 u; u.x = w0; u.y = w1;
        *(uint2*)(Xs + n * 512 + ((chunk ^ msk) << 4) + half8) = u;
      }
    }
  }
  __syncthreads();

  // ---- GEMM: acc[p][kr][j] over 8 c-slices, weights dbuf'd ----
  f32x4 acc[2][2][4];
#pragma unroll
  for (int p = 0; p < 2; ++p)
#pragma unroll
    for (int kr = 0; kr < 2; ++kr)
#pragma unroll
      for (int j = 0; j < 4; ++j) {
        acc[p][kr][j][0] = 0.f; acc[p][kr][j][1] = 0.f;
        acc[p][kr][j][2] = 0.f; acc[p][kr][j][3] = 0.f;
      }

  // read-side swizzle masks per j (n = 16j + col)
  int rmsk[4];
#pragma unroll
  for (int j = 0; j < 4; ++j) {
    const int n = 16 * j + col;
    rmsk[j] = (n ^ (n >> 2)) & 7;
  }

#pragma unroll
  for (int cs = 0; cs < 8; ++cs) {
    const int cur = cs & 1, nxt = cur ^ 1;
    if (cs + 1 < 8) {
      const int c0n = (cs + 1) * 32;
#pragma unroll
      for (int p = 0; p < 2; ++p)
#pragma unroll
        for (int kr = 0; kr < 2; ++kr) {
          const int k = wave * 32 + kr * 16 + col;
          afr[nxt][p][kr] =
              *(const short8*)(g_Wbf + p * 32768 + k * C_IN + c0n + quad * 8);
        }
    }
#pragma unroll
    for (int j = 0; j < 4; ++j) {
      const int chunk = 4 * cs + quad;
      short8 bfr = *(const short8*)(Xs + (16 * j + col) * 512 +
                                    ((chunk ^ rmsk[j]) << 4));
#pragma unroll
      for (int p = 0; p < 2; ++p)
#pragma unroll
        for (int kr = 0; kr < 2; ++kr)
          acc[p][kr][j] = __builtin_amdgcn_mfma_f32_16x16x32_bf16(
              afr[cur][p][kr], bfr, acc[p][kr][j], 0, 0, 0);
    }
  }
  __syncthreads();  // Xs reads done; reuse as epilogue bounce buffer

  // ---- epilogue: bias, LDS bounce, coalesced b128 stores ----
  short* PB = (short*)Xs;  // [64 n][128 k] shorts, granule-swizzled
#pragma unroll
  for (int p = 0; p < 2; ++p) {
    const float* bias = p ? phi_b : theta_b;
    short* dst0 = p ? Kt : Qt;
#pragma unroll
    for (int kr = 0; kr < 2; ++kr) {
      const int k0 = wave * 32 + kr * 16 + quad * 4;
      float4 bv = *(const float4*)(bias + k0);
      const int g = wave * 8 + kr * 4 + quad;
#pragma unroll
      for (int j = 0; j < 4; ++j) {
        const int nloc = j * 16 + col;
        f32x4 v = acc[p][kr][j];
        uint2 sv;
        sv.x = pk_bf16(v[0] + bv.x, v[1] + bv.y);
        sv.y = pk_bf16(v[2] + bv.z, v[3] + bv.w);
        const int gp = g ^ (nloc & 7) ^ (((nloc >> 3) & 1) << 3);
        *(uint2*)(PB + nloc * 128 + gp * 4) = sv;
      }
    }
    __syncthreads();
    {
      const int nloc = t >> 2, kseg = t & 3;
      const int xb = ((nloc >> 3) & 1) << 3;
      uint2 r8[8];
#pragma unroll
      for (int i = 0; i < 8; ++i) {
        const int gp = (kseg * 8 + i) ^ (nloc & 7) ^ xb;
        r8[i] = *(const uint2*)(PB + nloc * 128 + gp * 4);
      }
      short* dst = dst0 + ((size_t)b * N_SP + n0 + nloc) * K_INT + kseg * 32;
#pragma unroll
      for (int i2 = 0; i2 < 4; ++i2) {
        uint4 u;
        u.x = r8[2 * i2].x;     u.y = r8[2 * i2].y;
        u.z = r8[2 * i2 + 1].x; u.w = r8[2 * i2 + 1].y;
        *(uint4*)(dst + i2 * 8) = u;
      }
    }
    __syncthreads();  // before p=1 overwrites PB
  }
}

// ---------------------------------------------------------------------------
// Flash attention = R4-EXACT (measured 147.4us, absmax 4.88e-4, passed 2x).
// barrier_lgkm dropped (0 gain over __syncthreads, R8 vs R4) and setprio
// dropped (R10: nondeterministic failure -- it opens a timing race window).
// ---------------------------------------------------------------------------
__global__ __launch_bounds__(256) void attn_kernel(
    const short* __restrict__ Qt, const short* __restrict__ Kt,
    const short* __restrict__ Gbf, float* __restrict__ out)
{
  __shared__ __align__(16) char Kl[2][8192];          // [buf][32 m][128 k] swz
  __shared__ __align__(16) short Pblob[2][4][64][8];  // [buf][wave][lane][8]
  __shared__ float l_lds[64];

  const int b   = blockIdx.x / NTILE;
  const int qn0 = (blockIdx.x % NTILE) * 64;
  const int t = threadIdx.x;
  const int wave = t >> 6, lane = t & 63;
  const int col = lane & 15, quad = lane >> 4;

  const short* Ktb = Kt  + (size_t)b * N_SP * K_INT;
  const short* Gb  = Gbf + (size_t)b * C_IN * N_SP;

  // Q fragments in registers for the whole loop (B-operand layout: col=q)
  short8 qf[4];
  {
    const short* qb = Qt + ((size_t)b * N_SP + qn0 + wave * 16 + col) * K_INT + quad * 8;
#pragma unroll
    for (int kk = 0; kk < 4; ++kk) qf[kk] = *(const short8*)(qb + kk * 32);
  }

  f32x4 yacc[4][4];  // [q-tile][c-tile]
#pragma unroll
  for (int i = 0; i < 4; ++i)
#pragma unroll
    for (int j = 0; j < 4; ++j) {
      yacc[i][j][0] = 0.f; yacc[i][j][1] = 0.f;
      yacc[i][j][2] = 0.f; yacc[i][j][3] = 0.f;
    }
  f32x4 lacc;
  lacc[0] = 0.f; lacc[1] = 0.f; lacc[2] = 0.f; lacc[3] = 0.f;

  short8 ones;
#pragma unroll
  for (int j = 0; j < 8; ++j) ones[j] = (short)0x3F80;  // bf16 1.0

  const float SC2 = 0.12754859f;  // (1/sqrt(128)) * log2(e)

  // ---- K LDS offsets: phys(r,chunk) = r*256 + ((chunk ^ (r&7))<<4) ----
  const int KW = (t >> 4) * 256 + ((((t & 15) ^ ((t >> 4) & 7))) << 4);
  int KR0[4];
#pragma unroll
  for (int kk = 0; kk < 4; ++kk)
    KR0[kk] = col * 256 + ((((kk << 2) + quad) ^ (col & 7)) << 4);

  // ---- global offsets ----
  const int koff = (t >> 4) * K_INT + (t & 15) * 8;  // K stage rows t>>4 / +16
  const short* gbase = Gb + ((size_t)(wave * 64 + col)) * N_SP + quad * 8;

  // ---- prologue: tile0 -> Kl[0]; kr <- tile1; gA <- G tile0 ----
  short8 krA, krB;
  krA = *(const short8*)(Ktb + koff);
  krB = *(const short8*)(Ktb + 2048 + koff);
  *(short8*)(Kl[0] + KW) = krA;
  *(short8*)(Kl[0] + KW + 4096) = krB;
  krA = *(const short8*)(Ktb + 4096 + koff);
  krB = *(const short8*)(Ktb + 6144 + koff);
  short8 gA[4], gB[4];
#pragma unroll
  for (int ct = 0; ct < 4; ++ct)
    gA[ct] = *(const short8*)(gbase + (size_t)ct * 16 * N_SP);
  __syncthreads();

#define SUBITER(MTV, CUR, GC, GN)                                              \
  {                                                                            \
    /* 1. QK: S = K(tile MTV) x Q  (A-frags from LDS) */                       \
    f32x4 s0, s1;                                                              \
    s0[0] = 0.f; s0[1] = 0.f; s0[2] = 0.f; s0[3] = 0.f;                        \
    s1[0] = 0.f; s1[1] = 0.f; s1[2] = 0.f; s1[3] = 0.f;                        \
    _Pragma("unroll")                                                          \
    for (int kk = 0; kk < 4; ++kk) {                                           \
      short8 a0 = *(const short8*)(Kl[CUR] + KR0[kk]);                         \
      s0 = __builtin_amdgcn_mfma_f32_16x16x32_bf16(a0, qf[kk], s0, 0, 0, 0);   \
      short8 a1 = *(const short8*)(Kl[CUR] + KR0[kk] + 4096);                  \
      s1 = __builtin_amdgcn_mfma_f32_16x16x32_bf16(a1, qf[kk], s1, 0, 0, 0);   \
    }                                                                          \
    /* 2. softmax-lite + in-register transpose to A-fragment */                \
    unsigned u0 = pk_bf16(exp2f(s0[0] * SC2), exp2f(s0[1] * SC2));             \
    unsigned u1 = pk_bf16(exp2f(s0[2] * SC2), exp2f(s0[3] * SC2));             \
    unsigned u2 = pk_bf16(exp2f(s1[0] * SC2), exp2f(s1[1] * SC2));             \
    unsigned u3 = pk_bf16(exp2f(s1[2] * SC2), exp2f(s1[3] * SC2));             \
    asm("v_permlane32_swap_b32 %0, %1" : "+v"(u0), "+v"(u2));                  \
    asm("v_permlane32_swap_b32 %0, %1" : "+v"(u1), "+v"(u3));                  \
    asm("v_permlane16_swap_b32 %0, %1" : "+v"(u0), "+v"(u2));                  \
    asm("v_permlane16_swap_b32 %0, %1" : "+v"(u1), "+v"(u3));                  \
    unsigned uu[4] = {u0, u1, u2, u3};                                         \
    short8 pa; __builtin_memcpy(&pa, uu, 16);                                  \
    lacc = __builtin_amdgcn_mfma_f32_16x16x32_bf16(pa, ones, lacc, 0, 0, 0);   \
    /* 3. P exchange write (lane-linear, conflict-free) */                     \
    *(short8*)&Pblob[CUR][wave][lane][0] = pa;                                 \
    /* 4. K stage: tile MTV+1 -> Kl[CUR^1] (kr loaded LAST iter: landed) */    \
    if ((MTV) + 1 < MITER) {                                                   \
      *(short8*)(Kl[(CUR) ^ 1] + KW) = krA;                                    \
      *(short8*)(Kl[(CUR) ^ 1] + KW + 4096) = krB;                             \
    }                                                                          \
    /* 5. K global prefetch: tile MTV+2 (staged next iter) */                  \
    if ((MTV) + 2 < MITER) {                                                   \
      const short* kp = Ktb + (size_t)((MTV) + 2) * 4096 + koff;               \
      krA = *(const short8*)(kp);                                              \
      krB = *(const short8*)(kp + 2048);                                       \
    }                                                                          \
    /* 6. G global prefetch: tile MTV+1 (consumed next iter's PV) */           \
    if ((MTV) + 1 < MITER) {                                                   \
      _Pragma("unroll")                                                        \
      for (int ct = 0; ct < 4; ++ct)                                           \
        GN[ct] = *(const short8*)(gbase + (size_t)ct * 16 * N_SP +             \
                                  ((MTV) + 1) * 32);                           \
    }                                                                          \
    __syncthreads();                                                           \
    /* 7. PV: Y[q][c] += P[q][m] G^T[m][c]  (G regs, P lane-linear) */         \
    _Pragma("unroll")                                                          \
    for (int qt = 0; qt < 4; ++qt) {                                           \
      short8 paq = *(const short8*)&Pblob[CUR][qt][lane][0];                   \
      _Pragma("unroll")                                                        \
      for (int ct = 0; ct < 4; ++ct)                                           \
        yacc[qt][ct] = __builtin_amdgcn_mfma_f32_16x16x32_bf16(                \
            paq, GC[ct], yacc[qt][ct], 0, 0, 0);                               \
    }                                                                          \
  }

  for (int mt2 = 0; mt2 < MITER / 2; ++mt2) {
    SUBITER(2 * mt2,     0, gA, gB)
    SUBITER(2 * mt2 + 1, 1, gB, gA)
  }
#undef SUBITER

  // ---- l exchange: wave w holds l[16w + quad*4 + r] in lacc[r] ----
  if (col == 0) {
#pragma unroll
    for (int r = 0; r < 4; ++r) l_lds[wave * 16 + quad * 4 + r] = lacc[r];
  }
  __syncthreads();

  // ---- epilogue: normalize and store out[b][c][n]; c = wave*64+ct*16+col ----
#pragma unroll
  for (int qt = 0; qt < 4; ++qt) {
    float4 lq = *(const float4*)&l_lds[qt * 16 + quad * 4];
    float4 iv;
    iv.x = 1.0f / lq.x; iv.y = 1.0f / lq.y; iv.z = 1.0f / lq.z; iv.w = 1.0f / lq.w;
    const int nb = qn0 + qt * 16 + quad * 4;
#pragma unroll
    for (int ct = 0; ct < 4; ++ct) {
      const int c = wave * 64 + ct * 16 + col;
      f32x4 v = yacc[qt][ct];
      float4 o;
      o.x = v[0] * iv.x; o.y = v[1] * iv.y; o.z = v[2] * iv.z; o.w = v[3] * iv.w;
      *(float4*)(out + ((size_t)b * C_IN + c) * N_SP + nb) = o;
    }
  }
}

extern "C" void kernel_launch(void* const* d_in, const int* in_sizes, int n_in,
                              void* d_out, int out_size, void* d_ws, size_t ws_size,
                              hipStream_t stream) {
  const float* x  = (const float*)d_in[0];
  const float* tw = (const float*)d_in[1];
  const float* tb = (const float*)d_in[2];
  const float* pw = (const float*)d_in[3];
  const float* pb = (const float*)d_in[4];
  float* out = (float*)d_out;

  // workspace: Qt (9.4MB) | Kt (9.4MB) | Gbf (18.9MB) = 37.75 MB total
  short* Qt  = (short*)d_ws;
  short* Kt  = Qt + (size_t)B_SZ * N_SP * K_INT;
  short* Gbf = Kt + (size_t)B_SZ * N_SP * K_INT;

  wcvt_kernel<<<32, 256, 0, stream>>>(tw, pw);
  proj_kernel<<<B_SZ * NTILE, 256, 0, stream>>>(x, tb, pb, Qt, Kt, Gbf);
  attn_kernel<<<B_SZ * NTILE, 256, 0, stream>>>(Qt, Kt, Gbf, out);
}